// Round 1
// baseline (652.399 us; speedup 1.0000x reference)
//
#include <hip/hip_runtime.h>
#include <hip/hip_bf16.h>

#define BB 2
#define SS 4096
#define DD 512
#define HH 8
#define HDIM 64
#define WINW 128

__device__ __forceinline__ float bf_lo(unsigned int u) { return __uint_as_float(u << 16); }
__device__ __forceinline__ float bf_hi(unsigned int u) { return __uint_as_float(u & 0xffff0000u); }
__device__ __forceinline__ unsigned int f2bf(float f) {
    union { __hip_bfloat16 h; unsigned short u; } c;
    c.h = __float2bfloat16(f);
    return (unsigned int)c.u;
}
__device__ __forceinline__ float ldbf(const __hip_bfloat16* p) {
    union { __hip_bfloat16 h; unsigned short u; } c;
    c.h = *p;
    return __uint_as_float(((unsigned int)c.u) << 16);
}

// ---------------- QKV projection GEMM ----------------
// C(8192 x 1536) = X(8192x512) @ [Wq|Wk|Wv] + [bq|bk|bv]; output scattered to
// q/k/v planes, each (B,H,S,HD) bf16.
__global__ __launch_bounds__(256) void gemm_qkv(
    const float* __restrict__ X,
    const float* __restrict__ Wq, const float* __restrict__ bq,
    const float* __restrict__ Wk, const float* __restrict__ bk,
    const float* __restrict__ Wv, const float* __restrict__ bv,
    __hip_bfloat16* __restrict__ qkv)
{
    __shared__ float As[16][128];   // [k][m]
    __shared__ float Bs[16][128];   // [k][n]
    const int t  = threadIdx.x;
    const int tx = t & 15;
    const int ty = t >> 4;
    const int m0  = blockIdx.x * 128;
    const int n0g = blockIdx.y * 128;          // 0..1535
    const int which = n0g / DD;                // 0=q 1=k 2=v
    const int nc0   = n0g % DD;
    const float* Wp = (which == 0) ? Wq : (which == 1) ? Wk : Wv;
    const float* bp = (which == 0) ? bq : (which == 1) ? bk : bv;

    float acc[8][8];
    #pragma unroll
    for (int i = 0; i < 8; ++i)
        #pragma unroll
        for (int j = 0; j < 8; ++j) acc[i][j] = 0.f;

    for (int k0 = 0; k0 < DD; k0 += 16) {
        #pragma unroll
        for (int ld = 0; ld < 2; ++ld) {   // A tile 128x16
            int f = t + ld * 256;
            int row = f >> 2, c4 = f & 3;
            float4 av = *(const float4*)(X + (size_t)(m0 + row) * DD + k0 + c4 * 4);
            As[c4 * 4 + 0][row] = av.x;
            As[c4 * 4 + 1][row] = av.y;
            As[c4 * 4 + 2][row] = av.z;
            As[c4 * 4 + 3][row] = av.w;
        }
        #pragma unroll
        for (int ld = 0; ld < 2; ++ld) {   // B tile 16x128
            int f = t + ld * 256;
            int kk = f >> 5, c = f & 31;
            float4 bv4 = *(const float4*)(Wp + (size_t)(k0 + kk) * DD + nc0 + c * 4);
            *(float4*)&Bs[kk][c * 4] = bv4;
        }
        __syncthreads();
        #pragma unroll
        for (int kk = 0; kk < 16; ++kk) {
            float a[8], b[8];
            *(float4*)&a[0] = *(const float4*)&As[kk][ty * 8];
            *(float4*)&a[4] = *(const float4*)&As[kk][ty * 8 + 4];
            *(float4*)&b[0] = *(const float4*)&Bs[kk][tx * 8];
            *(float4*)&b[4] = *(const float4*)&Bs[kk][tx * 8 + 4];
            #pragma unroll
            for (int i = 0; i < 8; ++i)
                #pragma unroll
                for (int j = 0; j < 8; ++j)
                    acc[i][j] = fmaf(a[i], b[j], acc[i][j]);
        }
        __syncthreads();
    }

    const size_t plane = (size_t)BB * HH * SS * HDIM;
    __hip_bfloat16* outp = qkv + (size_t)which * plane;
    float bias[8];
    const int ncol = nc0 + tx * 8;
    #pragma unroll
    for (int j = 0; j < 8; ++j) bias[j] = bp[ncol + j];
    const int h  = ncol >> 6;
    const int hd = ncol & 63;
    #pragma unroll
    for (int i = 0; i < 8; ++i) {
        int m = m0 + ty * 8 + i;
        int b = m >> 12;           // /4096
        int s = m & 4095;
        size_t off = (((size_t)(b * HH + h) * SS) + s) * HDIM + hd;
        unsigned int w[4];
        #pragma unroll
        for (int j = 0; j < 4; ++j) {
            unsigned int lo = f2bf(acc[i][2 * j]     + bias[2 * j]);
            unsigned int hi = f2bf(acc[i][2 * j + 1] + bias[2 * j + 1]);
            w[j] = lo | (hi << 16);
        }
        *(uint4*)(outp + off) = make_uint4(w[0], w[1], w[2], w[3]);
    }
}

// ---------------- windowed attention ----------------
// 1 wave per query row; 4 waves per block.
__global__ __launch_bounds__(256) void attn_win(
    const __hip_bfloat16* __restrict__ qkv,
    float* __restrict__ aout)   // (B, S, D) fp32
{
    const int wave = threadIdx.x >> 6;
    const int lane = threadIdx.x & 63;
    const int row  = blockIdx.x * 4 + wave;   // over B*H*S
    const int i  = row & (SS - 1);
    const int bh = row >> 12;                  // b*H + h
    const int h = bh & (HH - 1);
    const int b = bh >> 3;

    const size_t plane = (size_t)BB * HH * SS * HDIM;
    const __hip_bfloat16* qp = qkv;
    const __hip_bfloat16* kp = qkv + plane;
    const __hip_bfloat16* vp = qkv + 2 * plane;
    const size_t base = (size_t)bh * SS * HDIM;

    __shared__ float qs[4][64];
    __shared__ float ps[4][256];

    // stage scaled q row
    qs[wave][lane] = ldbf(qp + base + (size_t)i * HDIM + lane) * 0.125f;
    __syncthreads();

    // scores: lane handles j = i-128 + t*64 + lane
    float sc[4];
    #pragma unroll
    for (int tj = 0; tj < 4; ++tj) {
        int j = i - WINW + tj * 64 + lane;
        float s = -1e30f;
        if (j >= 0 && j < SS) {
            const __hip_bfloat16* krow = kp + base + (size_t)j * HDIM;
            float a = 0.f;
            #pragma unroll
            for (int c = 0; c < 8; ++c) {
                uint4 kvu = *(const uint4*)(krow + c * 8);
                float4 q0 = *(const float4*)&qs[wave][c * 8];
                float4 q1 = *(const float4*)&qs[wave][c * 8 + 4];
                a += q0.x * bf_lo(kvu.x) + q0.y * bf_hi(kvu.x)
                   + q0.z * bf_lo(kvu.y) + q0.w * bf_hi(kvu.y)
                   + q1.x * bf_lo(kvu.z) + q1.y * bf_hi(kvu.z)
                   + q1.z * bf_lo(kvu.w) + q1.w * bf_hi(kvu.w);
            }
            s = a;
        }
        sc[tj] = s;
    }

    // softmax across the 256 window entries (4 per lane)
    float m4 = fmaxf(fmaxf(sc[0], sc[1]), fmaxf(sc[2], sc[3]));
    #pragma unroll
    for (int off = 32; off; off >>= 1) m4 = fmaxf(m4, __shfl_xor(m4, off));
    float e[4], sum = 0.f;
    #pragma unroll
    for (int tj = 0; tj < 4; ++tj) { e[tj] = __expf(sc[tj] - m4); sum += e[tj]; }
    #pragma unroll
    for (int off = 32; off; off >>= 1) sum += __shfl_xor(sum, off);
    float inv = 1.f / sum;
    #pragma unroll
    for (int tj = 0; tj < 4; ++tj) ps[wave][tj * 64 + lane] = e[tj] * inv;
    __syncthreads();

    // PV: lane = output dim
    float accv = 0.f;
    const __hip_bfloat16* vcol = vp + base + lane;
    for (int jj = 0; jj < 256; jj += 4) {
        float4 p4 = *(const float4*)&ps[wave][jj];
        int j0 = i - WINW + jj;
        if (j0 >= 0 && j0 + 3 < SS) {          // wave-uniform branch
            accv = fmaf(p4.x, ldbf(vcol + (size_t)(j0 + 0) * HDIM), accv);
            accv = fmaf(p4.y, ldbf(vcol + (size_t)(j0 + 1) * HDIM), accv);
            accv = fmaf(p4.z, ldbf(vcol + (size_t)(j0 + 2) * HDIM), accv);
            accv = fmaf(p4.w, ldbf(vcol + (size_t)(j0 + 3) * HDIM), accv);
        } else {
            float pv[4] = {p4.x, p4.y, p4.z, p4.w};
            #pragma unroll
            for (int u = 0; u < 4; ++u) {
                int j = j0 + u;
                if (j >= 0 && j < SS)
                    accv = fmaf(pv[u], ldbf(vcol + (size_t)j * HDIM), accv);
            }
        }
    }
    aout[((size_t)(b * SS + i)) * DD + h * HDIM + lane] = accv;
}

// ---------------- output projection GEMM ----------------
__global__ __launch_bounds__(256) void gemm_out(
    const float* __restrict__ A,     // (8192, 512) fp32
    const float* __restrict__ Wo, const float* __restrict__ bo,
    float* __restrict__ Out)         // (8192, 512) fp32
{
    __shared__ float As[16][128];
    __shared__ float Bs[16][128];
    const int t  = threadIdx.x;
    const int tx = t & 15;
    const int ty = t >> 4;
    const int m0 = blockIdx.x * 128;
    const int n0 = blockIdx.y * 128;

    float acc[8][8];
    #pragma unroll
    for (int i = 0; i < 8; ++i)
        #pragma unroll
        for (int j = 0; j < 8; ++j) acc[i][j] = 0.f;

    for (int k0 = 0; k0 < DD; k0 += 16) {
        #pragma unroll
        for (int ld = 0; ld < 2; ++ld) {
            int f = t + ld * 256;
            int row = f >> 2, c4 = f & 3;
            float4 av = *(const float4*)(A + (size_t)(m0 + row) * DD + k0 + c4 * 4);
            As[c4 * 4 + 0][row] = av.x;
            As[c4 * 4 + 1][row] = av.y;
            As[c4 * 4 + 2][row] = av.z;
            As[c4 * 4 + 3][row] = av.w;
        }
        #pragma unroll
        for (int ld = 0; ld < 2; ++ld) {
            int f = t + ld * 256;
            int kk = f >> 5, c = f & 31;
            float4 bv4 = *(const float4*)(Wo + (size_t)(k0 + kk) * DD + n0 + c * 4);
            *(float4*)&Bs[kk][c * 4] = bv4;
        }
        __syncthreads();
        #pragma unroll
        for (int kk = 0; kk < 16; ++kk) {
            float a[8], b[8];
            *(float4*)&a[0] = *(const float4*)&As[kk][ty * 8];
            *(float4*)&a[4] = *(const float4*)&As[kk][ty * 8 + 4];
            *(float4*)&b[0] = *(const float4*)&Bs[kk][tx * 8];
            *(float4*)&b[4] = *(const float4*)&Bs[kk][tx * 8 + 4];
            #pragma unroll
            for (int i = 0; i < 8; ++i)
                #pragma unroll
                for (int j = 0; j < 8; ++j)
                    acc[i][j] = fmaf(a[i], b[j], acc[i][j]);
        }
        __syncthreads();
    }

    const int ncol = n0 + tx * 8;
    float bias[8];
    #pragma unroll
    for (int j = 0; j < 8; ++j) bias[j] = bo[ncol + j];
    #pragma unroll
    for (int i = 0; i < 8; ++i) {
        int m = m0 + ty * 8 + i;
        float4 o0 = make_float4(acc[i][0] + bias[0], acc[i][1] + bias[1],
                                acc[i][2] + bias[2], acc[i][3] + bias[3]);
        float4 o1 = make_float4(acc[i][4] + bias[4], acc[i][5] + bias[5],
                                acc[i][6] + bias[6], acc[i][7] + bias[7]);
        *(float4*)(Out + (size_t)m * DD + ncol)     = o0;
        *(float4*)(Out + (size_t)m * DD + ncol + 4) = o1;
    }
}

extern "C" void kernel_launch(void* const* d_in, const int* in_sizes, int n_in,
                              void* d_out, int out_size, void* d_ws, size_t ws_size,
                              hipStream_t stream) {
    const float* x  = (const float*)d_in[0];
    const float* Wq = (const float*)d_in[1];
    const float* bq = (const float*)d_in[2];
    const float* Wk = (const float*)d_in[3];
    const float* bk = (const float*)d_in[4];
    const float* Wv = (const float*)d_in[5];
    const float* bv = (const float*)d_in[6];
    const float* Wo = (const float*)d_in[7];
    const float* bo = (const float*)d_in[8];
    float* out = (float*)d_out;

    char* ws = (char*)d_ws;
    __hip_bfloat16* qkv = (__hip_bfloat16*)ws;                                   // 25.2 MB
    float* aout = (float*)(ws + 3ull * BB * HH * SS * HDIM * sizeof(__hip_bfloat16)); // +16.8 MB

    dim3 blk(256);
    gemm_qkv<<<dim3(64, 12), blk, 0, stream>>>(x, Wq, bq, Wk, bk, Wv, bv, qkv);
    attn_win<<<dim3(BB * HH * SS / 4), blk, 0, stream>>>(qkv, aout);
    gemm_out<<<dim3(64, 4), blk, 0, stream>>>(aout, Wo, bo, out);
}

// Round 2
// 321.599 us; speedup vs baseline: 2.0286x; 2.0286x over previous
//
#include <hip/hip_runtime.h>
#include <hip/hip_bf16.h>

#define BB 2
#define SS 4096
#define DD 512
#define HH 8
#define HDIM 64
#define WINW 128

typedef __attribute__((ext_vector_type(8))) __bf16 bf16x8;
typedef __attribute__((ext_vector_type(4))) float f32x4;

__device__ __forceinline__ unsigned int f2bf(float f) {
    union { __hip_bfloat16 h; unsigned short u; } c;
    c.h = __float2bfloat16(f);
    return (unsigned int)c.u;
}

// ---------------- QKV projection GEMM ----------------
// C(8192 x 1536) = X(8192x512) @ [Wq|Wk|Wv] + bias.
// q,k planes: (B,H,S,HD) bf16. v plane: TRANSPOSED (B,H,HD,S) bf16.
__global__ __launch_bounds__(256) void gemm_qkv(
    const float* __restrict__ X,
    const float* __restrict__ Wq, const float* __restrict__ bq,
    const float* __restrict__ Wk, const float* __restrict__ bk,
    const float* __restrict__ Wv, const float* __restrict__ bv,
    __hip_bfloat16* __restrict__ qkv)
{
    __shared__ float As[16][128];   // [k][m]
    __shared__ float Bs[16][128];   // [k][n]
    const int t  = threadIdx.x;
    const int tx = t & 15;
    const int ty = t >> 4;
    const int m0  = blockIdx.x * 128;
    const int n0g = blockIdx.y * 128;          // 0..1535
    const int which = n0g / DD;                // 0=q 1=k 2=v
    const int nc0   = n0g % DD;
    const float* Wp = (which == 0) ? Wq : (which == 1) ? Wk : Wv;
    const float* bp = (which == 0) ? bq : (which == 1) ? bk : bv;

    float acc[8][8];
    #pragma unroll
    for (int i = 0; i < 8; ++i)
        #pragma unroll
        for (int j = 0; j < 8; ++j) acc[i][j] = 0.f;

    for (int k0 = 0; k0 < DD; k0 += 16) {
        #pragma unroll
        for (int ld = 0; ld < 2; ++ld) {   // A tile 128x16
            int f = t + ld * 256;
            int row = f >> 2, c4 = f & 3;
            float4 av = *(const float4*)(X + (size_t)(m0 + row) * DD + k0 + c4 * 4);
            As[c4 * 4 + 0][row] = av.x;
            As[c4 * 4 + 1][row] = av.y;
            As[c4 * 4 + 2][row] = av.z;
            As[c4 * 4 + 3][row] = av.w;
        }
        #pragma unroll
        for (int ld = 0; ld < 2; ++ld) {   // B tile 16x128
            int f = t + ld * 256;
            int kk = f >> 5, c = f & 31;
            float4 bv4 = *(const float4*)(Wp + (size_t)(k0 + kk) * DD + nc0 + c * 4);
            *(float4*)&Bs[kk][c * 4] = bv4;
        }
        __syncthreads();
        #pragma unroll
        for (int kk = 0; kk < 16; ++kk) {
            float a[8], b[8];
            *(float4*)&a[0] = *(const float4*)&As[kk][ty * 8];
            *(float4*)&a[4] = *(const float4*)&As[kk][ty * 8 + 4];
            *(float4*)&b[0] = *(const float4*)&Bs[kk][tx * 8];
            *(float4*)&b[4] = *(const float4*)&Bs[kk][tx * 8 + 4];
            #pragma unroll
            for (int i = 0; i < 8; ++i)
                #pragma unroll
                for (int j = 0; j < 8; ++j)
                    acc[i][j] = fmaf(a[i], b[j], acc[i][j]);
        }
        __syncthreads();
    }

    const size_t plane = (size_t)BB * HH * SS * HDIM;
    __hip_bfloat16* outp = qkv + (size_t)which * plane;
    float bias[8];
    const int ncol = nc0 + tx * 8;
    #pragma unroll
    for (int j = 0; j < 8; ++j) bias[j] = bp[ncol + j];

    if (which < 2) {
        // (B,H,S,HD) layout, row-contiguous uint4 stores
        const int h  = ncol >> 6;
        const int hd = ncol & 63;
        #pragma unroll
        for (int i = 0; i < 8; ++i) {
            int m = m0 + ty * 8 + i;
            int b = m >> 12;
            int s = m & 4095;
            size_t off = (((size_t)(b * HH + h) * SS) + s) * HDIM + hd;
            unsigned int w[4];
            #pragma unroll
            for (int j = 0; j < 4; ++j) {
                unsigned int lo = f2bf(acc[i][2 * j]     + bias[2 * j]);
                unsigned int hi = f2bf(acc[i][2 * j + 1] + bias[2 * j + 1]);
                w[j] = lo | (hi << 16);
            }
            *(uint4*)(outp + off) = make_uint4(w[0], w[1], w[2], w[3]);
        }
    } else {
        // V transposed: Vt[b][h][hd][s]; thread owns 8x8 block -> pack along s
        const int m_0 = m0 + ty * 8;
        const int b = m_0 >> 12;
        const int s0 = m_0 & 4095;
        #pragma unroll
        for (int j = 0; j < 8; ++j) {
            int nc = ncol + j;
            int h = nc >> 6, hd = nc & 63;
            float bj = bias[j];
            unsigned int w[4];
            #pragma unroll
            for (int u = 0; u < 4; ++u) {
                unsigned int lo = f2bf(acc[2 * u][j]     + bj);
                unsigned int hi = f2bf(acc[2 * u + 1][j] + bj);
                w[u] = lo | (hi << 16);
            }
            *(uint4*)(outp + ((size_t)(b * HH + h) * HDIM + hd) * SS + s0) =
                make_uint4(w[0], w[1], w[2], w[3]);
        }
    }
}

// ---------------- windowed attention, MFMA ----------------
// 4 waves/block; wave owns 16 q-rows of one (b,h) plane.
// 17 score tiles of 16 cols cover the union window [qbase-128, qbase+143].
__global__ __launch_bounds__(256) void attn_mfma(
    const __hip_bfloat16* __restrict__ qkv,
    float* __restrict__ aout)   // (B, S, D) fp32
{
    union ABu { bf16x8 v; uint2 d[2]; };

    __shared__ unsigned short plds[4][16][292];   // per-wave P, bf16 bits

    const int lane = threadIdx.x & 63;
    const int wave = threadIdx.x >> 6;
    const int col  = lane & 15;
    const int hi   = lane >> 4;
    const int k0   = hi * 4;

    const int qblk  = blockIdx.x;
    const int bh    = blockIdx.y;
    const int qbase = qblk * 64 + wave * 16;
    const int wbase = qbase - 2 * WINW >= 0 ? qbase - 128 : qbase - 128; // = qbase-128

    const size_t plane = (size_t)BB * HH * SS * HDIM;
    const unsigned short* qp = (const unsigned short*)qkv;
    const unsigned short* kp = qp + plane;
    const unsigned short* vt = qp + 2 * plane;    // Vt[bh][hd][s]
    const size_t base = (size_t)bh * SS * HDIM;

    // ---- Q A-fragments (two HD halves), lane row = col, k-pattern (hi*4 + e&3 + 16*(e>>2))
    const unsigned short* qrow = qp + base + (size_t)(qbase + col) * HDIM;
    ABu qaL, qaH;
    qaL.d[0] = *(const uint2*)(qrow + k0);
    qaL.d[1] = *(const uint2*)(qrow + k0 + 16);
    qaH.d[0] = *(const uint2*)(qrow + 32 + k0);
    qaH.d[1] = *(const uint2*)(qrow + 48 + k0);

    // ---- scores: 17 tiles x (2 mfma over HD)
    f32x4 sc[17];
    #pragma unroll
    for (int t = 0; t < 17; ++t) {
        int j = wbase + 16 * t + col;
        int jc = min(max(j, 0), SS - 1);
        const unsigned short* krow = kp + base + (size_t)jc * HDIM;
        ABu kbL, kbH;
        kbL.d[0] = *(const uint2*)(krow + k0);
        kbL.d[1] = *(const uint2*)(krow + k0 + 16);
        kbH.d[0] = *(const uint2*)(krow + 32 + k0);
        kbH.d[1] = *(const uint2*)(krow + 48 + k0);
        f32x4 z = {0.f, 0.f, 0.f, 0.f};
        f32x4 a = __builtin_amdgcn_mfma_f32_16x16x32_bf16(qaL.v, kbL.v, z, 0, 0, 0);
        sc[t] = __builtin_amdgcn_mfma_f32_16x16x32_bf16(qaH.v, kbH.v, a, 0, 0, 0);
    }

    // ---- mask + scale (C layout: row=(hi*4+r), col=lane&15)
    #pragma unroll
    for (int t = 0; t < 17; ++t) {
        int j = wbase + 16 * t + col;
        #pragma unroll
        for (int r = 0; r < 4; ++r) {
            int i = qbase + hi * 4 + r;
            bool ok = (j >= 0) && (j < SS) && (j >= i - WINW) && (j < i + WINW);
            sc[t][r] = ok ? sc[t][r] * 0.125f : -1e30f;
        }
    }

    // ---- softmax: reduce across lane bits 0..3 (the 16 cols)
    float mrow[4], srow[4];
    #pragma unroll
    for (int r = 0; r < 4; ++r) {
        float m = sc[0][r];
        #pragma unroll
        for (int t = 1; t < 17; ++t) m = fmaxf(m, sc[t][r]);
        m = fmaxf(m, __shfl_xor(m, 1));
        m = fmaxf(m, __shfl_xor(m, 2));
        m = fmaxf(m, __shfl_xor(m, 4));
        m = fmaxf(m, __shfl_xor(m, 8));
        mrow[r] = m;
    }
    #pragma unroll
    for (int r = 0; r < 4; ++r) {
        float s = 0.f;
        #pragma unroll
        for (int t = 0; t < 17; ++t) {
            float e = __expf(sc[t][r] - mrow[r]);
            sc[t][r] = e;
            s += e;
        }
        s += __shfl_xor(s, 1);
        s += __shfl_xor(s, 2);
        s += __shfl_xor(s, 4);
        s += __shfl_xor(s, 8);
        srow[r] = 1.f / s;
    }

    // ---- P -> LDS (bf16), rows = q, cols = window col; zero-pad 272..287
    #pragma unroll
    for (int t = 0; t < 17; ++t)
        #pragma unroll
        for (int r = 0; r < 4; ++r)
            plds[wave][hi * 4 + r][16 * t + col] =
                (unsigned short)f2bf(sc[t][r] * srow[r]);
    #pragma unroll
    for (int u = 0; u < 4; ++u)
        plds[wave][col][272 + hi * 4 + u] = 0;

    // ---- PV: out(16q x 64d) = P(16x288) @ V(288x64), 9 K-steps of 32
    f32x4 o[4];
    #pragma unroll
    for (int n = 0; n < 4; ++n) o[n] = (f32x4){0.f, 0.f, 0.f, 0.f};

    const unsigned short* prow = &plds[wave][col][0];   // A row = lane&15
    #pragma unroll
    for (int ks = 0; ks < 9; ++ks) {
        ABu pa;
        pa.d[0] = *(const uint2*)(prow + 32 * ks + k0);
        pa.d[1] = *(const uint2*)(prow + 32 * ks + k0 + 16);
        int w0 = wbase + 32 * ks + k0;
        int w0c = min(max(w0, 0), SS - 4);
        int w1c = min(max(w0 + 16, 0), SS - 4);
        #pragma unroll
        for (int n = 0; n < 4; ++n) {
            const unsigned short* vrow = vt + ((size_t)bh * HDIM + 16 * n + col) * SS;
            ABu vb;
            vb.d[0] = *(const uint2*)(vrow + w0c);
            vb.d[1] = *(const uint2*)(vrow + w1c);
            o[n] = __builtin_amdgcn_mfma_f32_16x16x32_bf16(pa.v, vb.v, o[n], 0, 0, 0);
        }
    }

    // ---- write attention output (B,S,D) fp32
    const int b = bh >> 3, h = bh & 7;
    #pragma unroll
    for (int n = 0; n < 4; ++n)
        #pragma unroll
        for (int r = 0; r < 4; ++r) {
            int i = qbase + hi * 4 + r;
            aout[((size_t)b * SS + i) * DD + h * HDIM + 16 * n + col] = o[n][r];
        }
}

// ---------------- output projection GEMM ----------------
__global__ __launch_bounds__(256) void gemm_out(
    const float* __restrict__ A,     // (8192, 512) fp32
    const float* __restrict__ Wo, const float* __restrict__ bo,
    float* __restrict__ Out)         // (8192, 512) fp32
{
    __shared__ float As[16][128];
    __shared__ float Bs[16][128];
    const int t  = threadIdx.x;
    const int tx = t & 15;
    const int ty = t >> 4;
    const int m0 = blockIdx.x * 128;
    const int n0 = blockIdx.y * 128;

    float acc[8][8];
    #pragma unroll
    for (int i = 0; i < 8; ++i)
        #pragma unroll
        for (int j = 0; j < 8; ++j) acc[i][j] = 0.f;

    for (int k0 = 0; k0 < DD; k0 += 16) {
        #pragma unroll
        for (int ld = 0; ld < 2; ++ld) {
            int f = t + ld * 256;
            int row = f >> 2, c4 = f & 3;
            float4 av = *(const float4*)(A + (size_t)(m0 + row) * DD + k0 + c4 * 4);
            As[c4 * 4 + 0][row] = av.x;
            As[c4 * 4 + 1][row] = av.y;
            As[c4 * 4 + 2][row] = av.z;
            As[c4 * 4 + 3][row] = av.w;
        }
        #pragma unroll
        for (int ld = 0; ld < 2; ++ld) {
            int f = t + ld * 256;
            int kk = f >> 5, c = f & 31;
            float4 bv4 = *(const float4*)(Wo + (size_t)(k0 + kk) * DD + n0 + c * 4);
            *(float4*)&Bs[kk][c * 4] = bv4;
        }
        __syncthreads();
        #pragma unroll
        for (int kk = 0; kk < 16; ++kk) {
            float a[8], b[8];
            *(float4*)&a[0] = *(const float4*)&As[kk][ty * 8];
            *(float4*)&a[4] = *(const float4*)&As[kk][ty * 8 + 4];
            *(float4*)&b[0] = *(const float4*)&Bs[kk][tx * 8];
            *(float4*)&b[4] = *(const float4*)&Bs[kk][tx * 8 + 4];
            #pragma unroll
            for (int i = 0; i < 8; ++i)
                #pragma unroll
                for (int j = 0; j < 8; ++j)
                    acc[i][j] = fmaf(a[i], b[j], acc[i][j]);
        }
        __syncthreads();
    }

    const int ncol = n0 + tx * 8;
    float bias[8];
    #pragma unroll
    for (int j = 0; j < 8; ++j) bias[j] = bo[ncol + j];
    #pragma unroll
    for (int i = 0; i < 8; ++i) {
        int m = m0 + ty * 8 + i;
        float4 o0 = make_float4(acc[i][0] + bias[0], acc[i][1] + bias[1],
                                acc[i][2] + bias[2], acc[i][3] + bias[3]);
        float4 o1 = make_float4(acc[i][4] + bias[4], acc[i][5] + bias[5],
                                acc[i][6] + bias[6], acc[i][7] + bias[7]);
        *(float4*)(Out + (size_t)m * DD + ncol)     = o0;
        *(float4*)(Out + (size_t)m * DD + ncol + 4) = o1;
    }
}

extern "C" void kernel_launch(void* const* d_in, const int* in_sizes, int n_in,
                              void* d_out, int out_size, void* d_ws, size_t ws_size,
                              hipStream_t stream) {
    const float* x  = (const float*)d_in[0];
    const float* Wq = (const float*)d_in[1];
    const float* bq = (const float*)d_in[2];
    const float* Wk = (const float*)d_in[3];
    const float* bk = (const float*)d_in[4];
    const float* Wv = (const float*)d_in[5];
    const float* bv = (const float*)d_in[6];
    const float* Wo = (const float*)d_in[7];
    const float* bo = (const float*)d_in[8];
    float* out = (float*)d_out;

    char* ws = (char*)d_ws;
    __hip_bfloat16* qkv = (__hip_bfloat16*)ws;                                   // 25.2 MB
    float* aout = (float*)(ws + 3ull * BB * HH * SS * HDIM * sizeof(__hip_bfloat16)); // +16.8 MB

    dim3 blk(256);
    gemm_qkv<<<dim3(64, 12), blk, 0, stream>>>(x, Wq, bq, Wk, bk, Wv, bv, qkv);
    attn_mfma<<<dim3(SS / 64, BB * HH), blk, 0, stream>>>(qkv, aout);
    gemm_out<<<dim3(64, 4), blk, 0, stream>>>(aout, Wo, bo, out);
}

// Round 3
// 93.117 us; speedup vs baseline: 7.0062x; 3.4537x over previous
//
#include <hip/hip_runtime.h>
#include <hip/hip_bf16.h>

#define BB 2
#define SS 4096
#define DD 512
#define HH 8
#define HDIM 64
#define WINW 128

typedef __attribute__((ext_vector_type(8))) __bf16 bf16x8;
typedef __attribute__((ext_vector_type(4))) float f32x4;
typedef unsigned short u16;

union Frag { bf16x8 v; uint4 u; };

__device__ __forceinline__ unsigned int f2bf(float f) {
    union { __hip_bfloat16 h; unsigned short u; } c;
    c.h = __float2bfloat16(f);
    return (unsigned int)c.u;
}

__device__ __forceinline__ void gload16(const void* g, void* l) {
    __builtin_amdgcn_global_load_lds(
        (const __attribute__((address_space(1))) unsigned int*)g,
        (__attribute__((address_space(3))) unsigned int*)l,
        16, 0, 0);
}

// ---------------- X -> bf16 ----------------
__global__ __launch_bounds__(256) void convert_x(
    const float* __restrict__ X, u16* __restrict__ Xb)
{
    int t = blockIdx.x * 256 + threadIdx.x;
    const float4 a = *(const float4*)(X + (size_t)t * 8);
    const float4 b = *(const float4*)(X + (size_t)t * 8 + 4);
    union { u16 s[8]; uint4 u; } p;
    p.s[0] = (u16)f2bf(a.x); p.s[1] = (u16)f2bf(a.y);
    p.s[2] = (u16)f2bf(a.z); p.s[3] = (u16)f2bf(a.w);
    p.s[4] = (u16)f2bf(b.x); p.s[5] = (u16)f2bf(b.y);
    p.s[6] = (u16)f2bf(b.z); p.s[7] = (u16)f2bf(b.w);
    *(uint4*)(Xb + (size_t)t * 8) = p.u;
}

// ---------------- W -> bf16 transposed ----------------
// src W (512x512, k-major). dst rows = output col n, contiguous k.
__global__ __launch_bounds__(256) void transpose_w(
    const float* __restrict__ Wq, const float* __restrict__ Wk,
    const float* __restrict__ Wv, const float* __restrict__ Wo,
    u16* __restrict__ Wt, u16* __restrict__ Wot)
{
    __shared__ float tile[64][65];
    const int which = blockIdx.z;
    const float* W = (which == 0) ? Wq : (which == 1) ? Wk : (which == 2) ? Wv : Wo;
    const int k0 = blockIdx.x * 64, n0 = blockIdx.y * 64;
    const int tr = threadIdx.x >> 6, tc = threadIdx.x & 63;
    #pragma unroll
    for (int r = 0; r < 16; ++r)
        tile[tr * 16 + r][tc] = W[(size_t)(k0 + tr * 16 + r) * 512 + n0 + tc];
    __syncthreads();
    u16* dst = (which < 3) ? (Wt + (size_t)which * 512 * 512) : Wot;
    #pragma unroll
    for (int r = 0; r < 16; ++r) {
        int nrow = n0 + tr * 16 + r;
        dst[(size_t)nrow * 512 + k0 + tc] = (u16)f2bf(tile[tc][tr * 16 + r]);
    }
}

// ---------------- bf16 MFMA GEMM ----------------
// C(M x N) = A(M x 512) @ Bt(N x 512)^T + bias.
// MODE 0: N=1536 qkv epilogue (q,k planes (B,H,S,HD) bf16; v transposed (B,H,HD,S) bf16)
// MODE 1: N=512, fp32 out (8192 x 512)
template<int MODE>
__global__ __launch_bounds__(256) void gemm_bf16(
    const u16* __restrict__ A, const u16* __restrict__ Bt,
    const float* __restrict__ b0, const float* __restrict__ b1,
    const float* __restrict__ b2, void* __restrict__ outv)
{
    __shared__ char lds[16384];
    char* lA = lds;
    char* lB = lds + 8192;
    const int lane = threadIdx.x & 63;
    const int wave = threadIdx.x >> 6;
    const int wm = wave >> 1, wn = wave & 1;
    const int col = lane & 15, hi = lane >> 4;
    const int m0 = blockIdx.x * 128;
    const int n0 = blockIdx.y * 128;

    f32x4 acc[4][4];
    #pragma unroll
    for (int i = 0; i < 4; ++i)
        #pragma unroll
        for (int j = 0; j < 4; ++j) acc[i][j] = (f32x4){0.f, 0.f, 0.f, 0.f};

    // staging: each wave loads rows wave*32..wave*32+31 of both tiles
    char* la0 = lA + (wave * 32) * 64;
    char* la1 = la0 + 16 * 64;
    char* lb0 = lB + (wave * 32) * 64;
    char* lb1 = lb0 + 16 * 64;
    const char* gA = (const char*)(A + (size_t)(m0 + wave * 32 + (lane >> 2)) * 512) + (lane & 3) * 16;
    const char* gB = (const char*)(Bt + (size_t)(n0 + wave * 32 + (lane >> 2)) * 512) + (lane & 3) * 16;

    for (int kt = 0; kt < 16; ++kt) {
        gload16(gA + kt * 64, la0);
        gload16(gA + 16 * 1024 + kt * 64, la1);
        gload16(gB + kt * 64, lb0);
        gload16(gB + 16 * 1024 + kt * 64, lb1);
        __syncthreads();
        Frag af[4], bf[4];
        #pragma unroll
        for (int ms = 0; ms < 4; ++ms)
            af[ms].u = *(const uint4*)(lA + (wm * 64 + ms * 16 + col) * 64 + hi * 16);
        #pragma unroll
        for (int ns = 0; ns < 4; ++ns)
            bf[ns].u = *(const uint4*)(lB + (wn * 64 + ns * 16 + col) * 64 + hi * 16);
        #pragma unroll
        for (int ms = 0; ms < 4; ++ms)
            #pragma unroll
            for (int ns = 0; ns < 4; ++ns)
                acc[ms][ns] = __builtin_amdgcn_mfma_f32_16x16x32_bf16(
                    af[ms].v, bf[ns].v, acc[ms][ns], 0, 0, 0);
        __syncthreads();
    }

    if (MODE == 0) {
        const size_t plane = (size_t)BB * HH * SS * HDIM;
        u16* qkv = (u16*)outv;
        #pragma unroll
        for (int ns = 0; ns < 4; ++ns) {
            int ngl0 = n0 + wn * 64 + ns * 16;
            int which = ngl0 >> 9;
            int nn0 = ngl0 & 511;
            int h = nn0 >> 6;
            int hd = (nn0 & 63) + col;
            const float* bp = (which == 0) ? b0 : (which == 1) ? b1 : b2;
            float bj = bp[nn0 + col];
            u16* base = qkv + (size_t)which * plane;
            if (which < 2) {
                #pragma unroll
                for (int ms = 0; ms < 4; ++ms) {
                    int m = m0 + wm * 64 + ms * 16 + hi * 4;
                    int b = m >> 12, s = m & 4095;
                    size_t off = ((size_t)(b * HH + h) * SS + s) * HDIM + hd;
                    #pragma unroll
                    for (int r = 0; r < 4; ++r)
                        base[off + (size_t)r * HDIM] = (u16)f2bf(acc[ms][ns][r] + bj);
                }
            } else {
                #pragma unroll
                for (int ms = 0; ms < 4; ++ms) {
                    int m = m0 + wm * 64 + ms * 16 + hi * 4;
                    int b = m >> 12, s0 = m & 4095;
                    unsigned int lo = f2bf(acc[ms][ns][0] + bj) | (f2bf(acc[ms][ns][1] + bj) << 16);
                    unsigned int hi2 = f2bf(acc[ms][ns][2] + bj) | (f2bf(acc[ms][ns][3] + bj) << 16);
                    *(uint2*)(base + ((size_t)(b * HH + h) * HDIM + hd) * SS + s0) =
                        make_uint2(lo, hi2);
                }
            }
        }
    } else {
        float* out = (float*)outv;
        #pragma unroll
        for (int ns = 0; ns < 4; ++ns) {
            int ngl0 = n0 + wn * 64 + ns * 16;
            float bj = b0[ngl0 + col];
            #pragma unroll
            for (int ms = 0; ms < 4; ++ms) {
                int m = m0 + wm * 64 + ms * 16 + hi * 4;
                #pragma unroll
                for (int r = 0; r < 4; ++r)
                    out[(size_t)(m + r) * 512 + ngl0 + col] = acc[ms][ns][r] + bj;
            }
        }
    }
}

// ---------------- windowed attention, MFMA ----------------
__global__ __launch_bounds__(256) void attn_mfma(
    const u16* __restrict__ qkv,
    u16* __restrict__ aout)   // (B, S, D) bf16
{
    __shared__ u16 plds[4][16][296];

    const int lane = threadIdx.x & 63;
    const int wave = threadIdx.x >> 6;
    const int col  = lane & 15;
    const int hi   = lane >> 4;

    const int qbase = blockIdx.x * 64 + wave * 16;
    const int bh    = blockIdx.y;
    const int wbase = qbase - 128;

    const size_t plane = (size_t)BB * HH * SS * HDIM;
    const u16* qp = qkv;
    const u16* kp = qp + plane;
    const u16* vt = qp + 2 * plane;    // Vt[bh][hd][s]
    const size_t base = (size_t)bh * SS * HDIM;

    // Q fragments: contiguous k map (hi*8 + e) per 32-wide half
    const u16* qrow = qp + base + (size_t)(qbase + col) * HDIM;
    Frag qaL, qaH;
    qaL.u = *(const uint4*)(qrow + hi * 8);
    qaH.u = *(const uint4*)(qrow + 32 + hi * 8);

    f32x4 sc[17];
    #pragma unroll
    for (int t = 0; t < 17; ++t) {
        int j = wbase + 16 * t + col;
        int jc = min(max(j, 0), SS - 1);
        const u16* krow = kp + base + (size_t)jc * HDIM;
        Frag kbL, kbH;
        kbL.u = *(const uint4*)(krow + hi * 8);
        kbH.u = *(const uint4*)(krow + 32 + hi * 8);
        f32x4 z = {0.f, 0.f, 0.f, 0.f};
        f32x4 a = __builtin_amdgcn_mfma_f32_16x16x32_bf16(qaL.v, kbL.v, z, 0, 0, 0);
        sc[t] = __builtin_amdgcn_mfma_f32_16x16x32_bf16(qaH.v, kbH.v, a, 0, 0, 0);
    }

    // mask + scale (C layout: row=(hi*4+r), col=lane&15)
    #pragma unroll
    for (int t = 0; t < 17; ++t) {
        int j = wbase + 16 * t + col;
        #pragma unroll
        for (int r = 0; r < 4; ++r) {
            int i = qbase + hi * 4 + r;
            bool ok = (j >= 0) && (j < SS) && (j >= i - WINW) && (j < i + WINW);
            sc[t][r] = ok ? sc[t][r] * 0.125f : -1e30f;
        }
    }

    float mrow[4], srow[4];
    #pragma unroll
    for (int r = 0; r < 4; ++r) {
        float m = sc[0][r];
        #pragma unroll
        for (int t = 1; t < 17; ++t) m = fmaxf(m, sc[t][r]);
        m = fmaxf(m, __shfl_xor(m, 1));
        m = fmaxf(m, __shfl_xor(m, 2));
        m = fmaxf(m, __shfl_xor(m, 4));
        m = fmaxf(m, __shfl_xor(m, 8));
        mrow[r] = m;
    }
    #pragma unroll
    for (int r = 0; r < 4; ++r) {
        float s = 0.f;
        #pragma unroll
        for (int t = 0; t < 17; ++t) {
            float e = __expf(sc[t][r] - mrow[r]);
            sc[t][r] = e;
            s += e;
        }
        s += __shfl_xor(s, 1);
        s += __shfl_xor(s, 2);
        s += __shfl_xor(s, 4);
        s += __shfl_xor(s, 8);
        srow[r] = 1.f / s;
    }

    #pragma unroll
    for (int t = 0; t < 17; ++t)
        #pragma unroll
        for (int r = 0; r < 4; ++r)
            plds[wave][hi * 4 + r][16 * t + col] = (u16)f2bf(sc[t][r] * srow[r]);
    #pragma unroll
    for (int u = 0; u < 4; ++u)
        plds[wave][col][272 + hi * 4 + u] = 0;

    f32x4 o[4];
    #pragma unroll
    for (int n = 0; n < 4; ++n) o[n] = (f32x4){0.f, 0.f, 0.f, 0.f};

    const u16* prow = &plds[wave][col][0];
    #pragma unroll
    for (int ks = 0; ks < 9; ++ks) {
        Frag pa;
        pa.u = *(const uint4*)(prow + 32 * ks + hi * 8);
        int w0 = wbase + 32 * ks + hi * 8;
        int w0c = min(max(w0, 0), SS - 8);
        #pragma unroll
        for (int n = 0; n < 4; ++n) {
            const u16* vrow = vt + ((size_t)bh * HDIM + 16 * n + col) * SS;
            Frag vb;
            vb.u = *(const uint4*)(vrow + w0c);
            o[n] = __builtin_amdgcn_mfma_f32_16x16x32_bf16(pa.v, vb.v, o[n], 0, 0, 0);
        }
    }

    const int b = bh >> 3, h = bh & 7;
    #pragma unroll
    for (int n = 0; n < 4; ++n)
        #pragma unroll
        for (int r = 0; r < 4; ++r) {
            int i = qbase + hi * 4 + r;
            aout[((size_t)b * SS + i) * DD + h * HDIM + 16 * n + col] = (u16)f2bf(o[n][r]);
        }
}

extern "C" void kernel_launch(void* const* d_in, const int* in_sizes, int n_in,
                              void* d_out, int out_size, void* d_ws, size_t ws_size,
                              hipStream_t stream) {
    const float* x  = (const float*)d_in[0];
    const float* Wq = (const float*)d_in[1];
    const float* bq = (const float*)d_in[2];
    const float* Wk = (const float*)d_in[3];
    const float* bk = (const float*)d_in[4];
    const float* Wv = (const float*)d_in[5];
    const float* bv = (const float*)d_in[6];
    const float* Wo = (const float*)d_in[7];
    const float* bo = (const float*)d_in[8];
    float* out = (float*)d_out;

    char* ws = (char*)d_ws;
    const size_t plane = (size_t)BB * HH * SS * HDIM;          // 4.19M elems
    u16* qkv = (u16*)ws;                                       // 3 planes, 25.2 MB
    u16* Xb  = (u16*)(ws + 3 * plane * sizeof(u16));           // 8.39 MB
    u16* aout = Xb;                                            // alias: Xb dead after gemm_qkv
    u16* Wt  = (u16*)(ws + 3 * plane * sizeof(u16) + (size_t)BB * SS * DD * sizeof(u16)); // 1.57 MB
    u16* Wot = Wt + (size_t)3 * 512 * 512;                     // 0.52 MB

    dim3 blk(256);
    convert_x<<<dim3(2048), blk, 0, stream>>>(x, Xb);
    transpose_w<<<dim3(8, 8, 4), blk, 0, stream>>>(Wq, Wk, Wv, Wo, Wt, Wot);
    gemm_bf16<0><<<dim3(64, 12), blk, 0, stream>>>(Xb, Wt, bq, bk, bv, qkv);
    attn_mfma<<<dim3(SS / 64, BB * HH), blk, 0, stream>>>(qkv, aout);
    gemm_bf16<1><<<dim3(64, 4), blk, 0, stream>>>(aout, Wot, bo, bo, bo, out);
}

// Round 4
// 77.030 us; speedup vs baseline: 8.4694x; 1.2088x over previous
//
#include <hip/hip_runtime.h>
#include <hip/hip_bf16.h>

#define BB 2
#define SS 4096
#define DD 512
#define HH 8
#define HDIM 64
#define WINW 128

typedef __attribute__((ext_vector_type(8))) __bf16 bf16x8;
typedef __attribute__((ext_vector_type(4))) float f32x4;
typedef unsigned short u16;

union Frag { bf16x8 v; uint4 u; };

__device__ __forceinline__ unsigned int f2bf(float f) {
    union { __hip_bfloat16 h; unsigned short u; } c;
    c.h = __float2bfloat16(f);
    return (unsigned int)c.u;
}

__device__ __forceinline__ void gload16(const void* g, void* l) {
    __builtin_amdgcn_global_load_lds(
        (const __attribute__((address_space(1))) unsigned int*)g,
        (__attribute__((address_space(3))) unsigned int*)l,
        16, 0, 0);
}

// ---------------- X -> bf16 ----------------
__global__ __launch_bounds__(256) void convert_x(
    const float* __restrict__ X, u16* __restrict__ Xb)
{
    int t = blockIdx.x * 256 + threadIdx.x;
    const float4 a = *(const float4*)(X + (size_t)t * 8);
    const float4 b = *(const float4*)(X + (size_t)t * 8 + 4);
    union { u16 s[8]; uint4 u; } p;
    p.s[0] = (u16)f2bf(a.x); p.s[1] = (u16)f2bf(a.y);
    p.s[2] = (u16)f2bf(a.z); p.s[3] = (u16)f2bf(a.w);
    p.s[4] = (u16)f2bf(b.x); p.s[5] = (u16)f2bf(b.y);
    p.s[6] = (u16)f2bf(b.z); p.s[7] = (u16)f2bf(b.w);
    *(uint4*)(Xb + (size_t)t * 8) = p.u;
}

// ---------------- W -> bf16 transposed ----------------
__global__ __launch_bounds__(256) void transpose_w(
    const float* __restrict__ Wq, const float* __restrict__ Wk,
    const float* __restrict__ Wv, const float* __restrict__ Wo,
    u16* __restrict__ Wt, u16* __restrict__ Wot)
{
    __shared__ float tile[64][65];
    const int which = blockIdx.z;
    const float* W = (which == 0) ? Wq : (which == 1) ? Wk : (which == 2) ? Wv : Wo;
    const int k0 = blockIdx.x * 64, n0 = blockIdx.y * 64;
    const int tr = threadIdx.x >> 6, tc = threadIdx.x & 63;
    #pragma unroll
    for (int r = 0; r < 16; ++r)
        tile[tr * 16 + r][tc] = W[(size_t)(k0 + tr * 16 + r) * 512 + n0 + tc];
    __syncthreads();
    u16* dst = (which < 3) ? (Wt + (size_t)which * 512 * 512) : Wot;
    #pragma unroll
    for (int r = 0; r < 16; ++r) {
        int nrow = n0 + tr * 16 + r;
        dst[(size_t)nrow * 512 + k0 + tc] = (u16)f2bf(tile[tc][tr * 16 + r]);
    }
}

// ---------------- bf16 MFMA GEMM ----------------
template<int MODE>
__global__ __launch_bounds__(256) void gemm_bf16(
    const u16* __restrict__ A, const u16* __restrict__ Bt,
    const float* __restrict__ b0, const float* __restrict__ b1,
    const float* __restrict__ b2, void* __restrict__ outv)
{
    __shared__ char lds[16384];
    char* lA = lds;
    char* lB = lds + 8192;
    const int lane = threadIdx.x & 63;
    const int wave = threadIdx.x >> 6;
    const int wm = wave >> 1, wn = wave & 1;
    const int col = lane & 15, hi = lane >> 4;
    const int m0 = blockIdx.x * 128;
    const int n0 = blockIdx.y * 128;

    f32x4 acc[4][4];
    #pragma unroll
    for (int i = 0; i < 4; ++i)
        #pragma unroll
        for (int j = 0; j < 4; ++j) acc[i][j] = (f32x4){0.f, 0.f, 0.f, 0.f};

    char* la0 = lA + (wave * 32) * 64;
    char* la1 = la0 + 16 * 64;
    char* lb0 = lB + (wave * 32) * 64;
    char* lb1 = lb0 + 16 * 64;
    const char* gA = (const char*)(A + (size_t)(m0 + wave * 32 + (lane >> 2)) * 512) + (lane & 3) * 16;
    const char* gB = (const char*)(Bt + (size_t)(n0 + wave * 32 + (lane >> 2)) * 512) + (lane & 3) * 16;

    for (int kt = 0; kt < 16; ++kt) {
        gload16(gA + kt * 64, la0);
        gload16(gA + 16 * 1024 + kt * 64, la1);
        gload16(gB + kt * 64, lb0);
        gload16(gB + 16 * 1024 + kt * 64, lb1);
        __syncthreads();
        Frag af[4], bf[4];
        #pragma unroll
        for (int ms = 0; ms < 4; ++ms)
            af[ms].u = *(const uint4*)(lA + (wm * 64 + ms * 16 + col) * 64 + hi * 16);
        #pragma unroll
        for (int ns = 0; ns < 4; ++ns)
            bf[ns].u = *(const uint4*)(lB + (wn * 64 + ns * 16 + col) * 64 + hi * 16);
        #pragma unroll
        for (int ms = 0; ms < 4; ++ms)
            #pragma unroll
            for (int ns = 0; ns < 4; ++ns)
                acc[ms][ns] = __builtin_amdgcn_mfma_f32_16x16x32_bf16(
                    af[ms].v, bf[ns].v, acc[ms][ns], 0, 0, 0);
        __syncthreads();
    }

    if (MODE == 0) {
        const size_t plane = (size_t)BB * HH * SS * HDIM;
        u16* qkv = (u16*)outv;
        #pragma unroll
        for (int ns = 0; ns < 4; ++ns) {
            int ngl0 = n0 + wn * 64 + ns * 16;
            int which = ngl0 >> 9;
            int nn0 = ngl0 & 511;
            int h = nn0 >> 6;
            int hd = (nn0 & 63) + col;
            const float* bp = (which == 0) ? b0 : (which == 1) ? b1 : b2;
            float bj = bp[nn0 + col];
            u16* base = qkv + (size_t)which * plane;
            if (which < 2) {
                #pragma unroll
                for (int ms = 0; ms < 4; ++ms) {
                    int m = m0 + wm * 64 + ms * 16 + hi * 4;
                    int b = m >> 12, s = m & 4095;
                    size_t off = ((size_t)(b * HH + h) * SS + s) * HDIM + hd;
                    #pragma unroll
                    for (int r = 0; r < 4; ++r)
                        base[off + (size_t)r * HDIM] = (u16)f2bf(acc[ms][ns][r] + bj);
                }
            } else {
                #pragma unroll
                for (int ms = 0; ms < 4; ++ms) {
                    int m = m0 + wm * 64 + ms * 16 + hi * 4;
                    int b = m >> 12, s0 = m & 4095;
                    unsigned int lo = f2bf(acc[ms][ns][0] + bj) | (f2bf(acc[ms][ns][1] + bj) << 16);
                    unsigned int hi2 = f2bf(acc[ms][ns][2] + bj) | (f2bf(acc[ms][ns][3] + bj) << 16);
                    *(uint2*)(base + ((size_t)(b * HH + h) * HDIM + hd) * SS + s0) =
                        make_uint2(lo, hi2);
                }
            }
        }
    } else {
        float* out = (float*)outv;
        #pragma unroll
        for (int ns = 0; ns < 4; ++ns) {
            int ngl0 = n0 + wn * 64 + ns * 16;
            float bj = b0[ngl0 + col];
            #pragma unroll
            for (int ms = 0; ms < 4; ++ms) {
                int m = m0 + wm * 64 + ms * 16 + hi * 4;
                #pragma unroll
                for (int r = 0; r < 4; ++r)
                    out[(size_t)(m + r) * 512 + ngl0 + col] = acc[ms][ns][r] + bj;
            }
        }
    }
}

// ---------------- windowed attention, MFMA + LDS K-stage ----------------
// Block = 64 q rows (4 waves x 16). K window union [qb-128, qb+191] = 320 rows
// staged contiguously in LDS with granule XOR-swizzle (write via pre-swizzled
// global source, read with same XOR). P overlays the K buffer after a barrier.
__global__ __launch_bounds__(256) void attn_mfma(
    const u16* __restrict__ qkv,
    u16* __restrict__ aout)   // (B, S, D) bf16
{
    __shared__ char kbuf[40960];          // 320 rows x 128B; P overlays after barrier

    const int tid  = threadIdx.x;
    const int lane = tid & 63;
    const int wave = tid >> 6;
    const int col  = lane & 15;
    const int hi   = lane >> 4;

    // XCD-aware swizzle: xcd p%8 gets logical chunk of 128 consecutive ids
    const int p = blockIdx.x;             // 0..1023
    const int l = (p & 7) * 128 + (p >> 3);
    const int qblk = l & 63;
    const int bh   = l >> 6;

    const int qbase  = qblk * 64 + wave * 16;
    const int wbaseB = qblk * 64 - 128;   // block window base
    const int wbase  = qbase - 128;       // wave window base

    const size_t plane = (size_t)BB * HH * SS * HDIM;
    const u16* qp = qkv;
    const u16* kp = qp + plane;
    const u16* vt = qp + 2 * plane;       // Vt[bh][hd][s]
    const size_t base = (size_t)bh * SS * HDIM;

    // Q fragments (issue before staging to overlap)
    const u16* qrow = qp + base + (size_t)(qbase + col) * HDIM;
    Frag qaL, qaH;
    qaL.u = *(const uint4*)(qrow + hi * 8);
    qaH.u = *(const uint4*)(qrow + 32 + hi * 8);

    // ---- cooperative K staging: 2560 granules of 16B, 10 rounds x 256 threads
    // LDS[r][g] = K[clamp(wbaseB+r)][g ^ (r&7)]  (involution per row)
    #pragma unroll
    for (int rnd = 0; rnd < 10; ++rnd) {
        int f = rnd * 256 + tid;
        int r = f >> 3, g = f & 7;
        int srow = min(max(wbaseB + r, 0), SS - 1);
        int sg = g ^ (r & 7);
        const u16* src = kp + base + (size_t)srow * HDIM + sg * 8;
        gload16(src, kbuf + (rnd * 256 + wave * 64) * 16);
    }
    __syncthreads();

    // ---- scores from LDS (granule-XOR read back)
    const int c7 = col & 7;
    f32x4 sc[17];
    #pragma unroll
    for (int t = 0; t < 17; ++t) {
        int wr = wave * 16 + 16 * t + col;        // 0..319
        const char* kb = kbuf + wr * 128;
        Frag kbL, kbH;
        kbL.u = *(const uint4*)(kb + ((hi ^ c7) * 16));
        kbH.u = *(const uint4*)(kb + (((hi | 4) ^ c7) * 16));
        f32x4 z = {0.f, 0.f, 0.f, 0.f};
        f32x4 a = __builtin_amdgcn_mfma_f32_16x16x32_bf16(qaL.v, kbL.v, z, 0, 0, 0);
        sc[t] = __builtin_amdgcn_mfma_f32_16x16x32_bf16(qaH.v, kbH.v, a, 0, 0, 0);
    }

    // ---- mask + scale
    #pragma unroll
    for (int t = 0; t < 17; ++t) {
        int j = wbase + 16 * t + col;
        #pragma unroll
        for (int r = 0; r < 4; ++r) {
            int i = qbase + hi * 4 + r;
            bool ok = (j >= 0) && (j < SS) && (j >= i - WINW) && (j < i + WINW);
            sc[t][r] = ok ? sc[t][r] * 0.125f : -1e30f;
        }
    }

    // ---- softmax (reduce across lane bits 0..3)
    float mrow[4], srow4[4];
    #pragma unroll
    for (int r = 0; r < 4; ++r) {
        float m = sc[0][r];
        #pragma unroll
        for (int t = 1; t < 17; ++t) m = fmaxf(m, sc[t][r]);
        m = fmaxf(m, __shfl_xor(m, 1));
        m = fmaxf(m, __shfl_xor(m, 2));
        m = fmaxf(m, __shfl_xor(m, 4));
        m = fmaxf(m, __shfl_xor(m, 8));
        mrow[r] = m;
    }
    #pragma unroll
    for (int r = 0; r < 4; ++r) {
        float s = 0.f;
        #pragma unroll
        for (int t = 0; t < 17; ++t) {
            float e = __expf(sc[t][r] - mrow[r]);
            sc[t][r] = e;
            s += e;
        }
        s += __shfl_xor(s, 1);
        s += __shfl_xor(s, 2);
        s += __shfl_xor(s, 4);
        s += __shfl_xor(s, 8);
        srow4[r] = 1.f / s;
    }

    // ---- all waves done reading K; P overlays kbuf
    __syncthreads();
    u16* plds = (u16*)kbuf + (size_t)wave * 16 * 296;   // [16][296] per wave

    #pragma unroll
    for (int t = 0; t < 17; ++t)
        #pragma unroll
        for (int r = 0; r < 4; ++r)
            plds[(hi * 4 + r) * 296 + 16 * t + col] = (u16)f2bf(sc[t][r] * srow4[r]);
    #pragma unroll
    for (int u = 0; u < 4; ++u)
        plds[col * 296 + 272 + hi * 4 + u] = 0;

    // ---- PV: own-wave P (in-wave LDS ordering), V from global (L2 via swizzle)
    f32x4 o[4];
    #pragma unroll
    for (int n = 0; n < 4; ++n) o[n] = (f32x4){0.f, 0.f, 0.f, 0.f};

    const u16* prow = plds + col * 296;
    #pragma unroll
    for (int ks = 0; ks < 9; ++ks) {
        Frag pa;
        pa.u = *(const uint4*)(prow + 32 * ks + hi * 8);
        int w0 = wbase + 32 * ks + hi * 8;
        int w0c = min(max(w0, 0), SS - 8);
        #pragma unroll
        for (int n = 0; n < 4; ++n) {
            const u16* vrow = vt + ((size_t)bh * HDIM + 16 * n + col) * SS;
            Frag vb;
            vb.u = *(const uint4*)(vrow + w0c);
            o[n] = __builtin_amdgcn_mfma_f32_16x16x32_bf16(pa.v, vb.v, o[n], 0, 0, 0);
        }
    }

    const int b = bh >> 3, h = bh & 7;
    #pragma unroll
    for (int n = 0; n < 4; ++n)
        #pragma unroll
        for (int r = 0; r < 4; ++r) {
            int i = qbase + hi * 4 + r;
            aout[((size_t)b * SS + i) * DD + h * HDIM + 16 * n + col] = (u16)f2bf(o[n][r]);
        }
}

extern "C" void kernel_launch(void* const* d_in, const int* in_sizes, int n_in,
                              void* d_out, int out_size, void* d_ws, size_t ws_size,
                              hipStream_t stream) {
    const float* x  = (const float*)d_in[0];
    const float* Wq = (const float*)d_in[1];
    const float* bq = (const float*)d_in[2];
    const float* Wk = (const float*)d_in[3];
    const float* bk = (const float*)d_in[4];
    const float* Wv = (const float*)d_in[5];
    const float* bv = (const float*)d_in[6];
    const float* Wo = (const float*)d_in[7];
    const float* bo = (const float*)d_in[8];
    float* out = (float*)d_out;

    char* ws = (char*)d_ws;
    const size_t plane = (size_t)BB * HH * SS * HDIM;
    u16* qkv = (u16*)ws;
    u16* Xb  = (u16*)(ws + 3 * plane * sizeof(u16));
    u16* aout = Xb;                                     // alias: Xb dead after gemm_qkv
    u16* Wt  = (u16*)(ws + 3 * plane * sizeof(u16) + (size_t)BB * SS * DD * sizeof(u16));
    u16* Wot = Wt + (size_t)3 * 512 * 512;

    dim3 blk(256);
    convert_x<<<dim3(2048), blk, 0, stream>>>(x, Xb);
    transpose_w<<<dim3(8, 8, 4), blk, 0, stream>>>(Wq, Wk, Wv, Wo, Wt, Wot);
    gemm_bf16<0><<<dim3(64, 12), blk, 0, stream>>>(Xb, Wt, bq, bk, bv, qkv);
    attn_mfma<<<dim3(1024), blk, 0, stream>>>(qkv, aout);
    gemm_bf16<1><<<dim3(64, 4), blk, 0, stream>>>(aout, Wot, bo, bo, bo, out);
}

// Round 5
// 67.009 us; speedup vs baseline: 9.7360x; 1.1495x over previous
//
#include <hip/hip_runtime.h>
#include <hip/hip_bf16.h>

#define BB 2
#define SS 4096
#define DD 512
#define HH 8
#define HDIM 64
#define WINW 128

typedef __attribute__((ext_vector_type(8))) __bf16 bf16x8;
typedef __attribute__((ext_vector_type(4))) float f32x4;
typedef unsigned short u16;

union Frag { bf16x8 v; uint4 u; };

__device__ __forceinline__ unsigned int f2bf(float f) {
    union { __hip_bfloat16 h; unsigned short u; } c;
    c.h = __float2bfloat16(f);
    return (unsigned int)c.u;
}

__device__ __forceinline__ void gload16(const void* g, void* l) {
    __builtin_amdgcn_global_load_lds(
        (const __attribute__((address_space(1))) unsigned int*)g,
        (__attribute__((address_space(3))) unsigned int*)l,
        16, 0, 0);
}

// ---------------- X -> bf16 ----------------
__global__ __launch_bounds__(256) void convert_x(
    const float* __restrict__ X, u16* __restrict__ Xb)
{
    int t = blockIdx.x * 256 + threadIdx.x;
    const float4 a = *(const float4*)(X + (size_t)t * 8);
    const float4 b = *(const float4*)(X + (size_t)t * 8 + 4);
    union { u16 s[8]; uint4 u; } p;
    p.s[0] = (u16)f2bf(a.x); p.s[1] = (u16)f2bf(a.y);
    p.s[2] = (u16)f2bf(a.z); p.s[3] = (u16)f2bf(a.w);
    p.s[4] = (u16)f2bf(b.x); p.s[5] = (u16)f2bf(b.y);
    p.s[6] = (u16)f2bf(b.z); p.s[7] = (u16)f2bf(b.w);
    *(uint4*)(Xb + (size_t)t * 8) = p.u;
}

// ---------------- W -> bf16 transposed ----------------
__global__ __launch_bounds__(256) void transpose_w(
    const float* __restrict__ Wq, const float* __restrict__ Wk,
    const float* __restrict__ Wv, const float* __restrict__ Wo,
    u16* __restrict__ Wt, u16* __restrict__ Wot)
{
    __shared__ float tile[64][65];
    const int which = blockIdx.z;
    const float* W = (which == 0) ? Wq : (which == 1) ? Wk : (which == 2) ? Wv : Wo;
    const int k0 = blockIdx.x * 64, n0 = blockIdx.y * 64;
    const int tr = threadIdx.x >> 6, tc = threadIdx.x & 63;
    #pragma unroll
    for (int r = 0; r < 16; ++r)
        tile[tr * 16 + r][tc] = W[(size_t)(k0 + tr * 16 + r) * 512 + n0 + tc];
    __syncthreads();
    u16* dst = (which < 3) ? (Wt + (size_t)which * 512 * 512) : Wot;
    #pragma unroll
    for (int r = 0; r < 16; ++r) {
        int nrow = n0 + tr * 16 + r;
        dst[(size_t)nrow * 512 + k0 + tc] = (u16)f2bf(tile[tc][tr * 16 + r]);
    }
}

// ---------------- bf16 MFMA GEMM ----------------
template<int MODE>
__global__ __launch_bounds__(256) void gemm_bf16(
    const u16* __restrict__ A, const u16* __restrict__ Bt,
    const float* __restrict__ b0, const float* __restrict__ b1,
    const float* __restrict__ b2, void* __restrict__ outv)
{
    __shared__ char lds[16384];
    char* lA = lds;
    char* lB = lds + 8192;
    const int lane = threadIdx.x & 63;
    const int wave = threadIdx.x >> 6;
    const int wm = wave >> 1, wn = wave & 1;
    const int col = lane & 15, hi = lane >> 4;
    const int m0 = blockIdx.x * 128;
    const int n0 = blockIdx.y * 128;

    f32x4 acc[4][4];
    #pragma unroll
    for (int i = 0; i < 4; ++i)
        #pragma unroll
        for (int j = 0; j < 4; ++j) acc[i][j] = (f32x4){0.f, 0.f, 0.f, 0.f};

    char* la0 = lA + (wave * 32) * 64;
    char* la1 = la0 + 16 * 64;
    char* lb0 = lB + (wave * 32) * 64;
    char* lb1 = lb0 + 16 * 64;
    const char* gA = (const char*)(A + (size_t)(m0 + wave * 32 + (lane >> 2)) * 512) + (lane & 3) * 16;
    const char* gB = (const char*)(Bt + (size_t)(n0 + wave * 32 + (lane >> 2)) * 512) + (lane & 3) * 16;

    for (int kt = 0; kt < 16; ++kt) {
        gload16(gA + kt * 64, la0);
        gload16(gA + 16 * 1024 + kt * 64, la1);
        gload16(gB + kt * 64, lb0);
        gload16(gB + 16 * 1024 + kt * 64, lb1);
        __syncthreads();
        Frag af[4], bf[4];
        #pragma unroll
        for (int ms = 0; ms < 4; ++ms)
            af[ms].u = *(const uint4*)(lA + (wm * 64 + ms * 16 + col) * 64 + hi * 16);
        #pragma unroll
        for (int ns = 0; ns < 4; ++ns)
            bf[ns].u = *(const uint4*)(lB + (wn * 64 + ns * 16 + col) * 64 + hi * 16);
        __builtin_amdgcn_s_setprio(1);
        #pragma unroll
        for (int ms = 0; ms < 4; ++ms)
            #pragma unroll
            for (int ns = 0; ns < 4; ++ns)
                acc[ms][ns] = __builtin_amdgcn_mfma_f32_16x16x32_bf16(
                    af[ms].v, bf[ns].v, acc[ms][ns], 0, 0, 0);
        __builtin_amdgcn_s_setprio(0);
        __syncthreads();
    }

    if (MODE == 0) {
        const size_t plane = (size_t)BB * HH * SS * HDIM;
        u16* qkv = (u16*)outv;
        #pragma unroll
        for (int ns = 0; ns < 4; ++ns) {
            int ngl0 = n0 + wn * 64 + ns * 16;
            int which = ngl0 >> 9;
            int nn0 = ngl0 & 511;
            int h = nn0 >> 6;
            int hd = (nn0 & 63) + col;
            const float* bp = (which == 0) ? b0 : (which == 1) ? b1 : b2;
            float bj = bp[nn0 + col];
            u16* base = qkv + (size_t)which * plane;
            if (which < 2) {
                #pragma unroll
                for (int ms = 0; ms < 4; ++ms) {
                    int m = m0 + wm * 64 + ms * 16 + hi * 4;
                    int b = m >> 12, s = m & 4095;
                    size_t off = ((size_t)(b * HH + h) * SS + s) * HDIM + hd;
                    #pragma unroll
                    for (int r = 0; r < 4; ++r)
                        base[off + (size_t)r * HDIM] = (u16)f2bf(acc[ms][ns][r] + bj);
                }
            } else {
                #pragma unroll
                for (int ms = 0; ms < 4; ++ms) {
                    int m = m0 + wm * 64 + ms * 16 + hi * 4;
                    int b = m >> 12, s0 = m & 4095;
                    unsigned int lo = f2bf(acc[ms][ns][0] + bj) | (f2bf(acc[ms][ns][1] + bj) << 16);
                    unsigned int hi2 = f2bf(acc[ms][ns][2] + bj) | (f2bf(acc[ms][ns][3] + bj) << 16);
                    *(uint2*)(base + ((size_t)(b * HH + h) * HDIM + hd) * SS + s0) =
                        make_uint2(lo, hi2);
                }
            }
        }
    } else {
        float* out = (float*)outv;
        #pragma unroll
        for (int ns = 0; ns < 4; ++ns) {
            int ngl0 = n0 + wn * 64 + ns * 16;
            float bj = b0[ngl0 + col];
            #pragma unroll
            for (int ms = 0; ms < 4; ++ms) {
                int m = m0 + wm * 64 + ms * 16 + hi * 4;
                #pragma unroll
                for (int r = 0; r < 4; ++r)
                    out[(size_t)(m + r) * 512 + ngl0 + col] = acc[ms][ns][r] + bj;
            }
        }
    }
}

// ---------------- windowed attention: MFMA, K+V both LDS-staged ----------------
// Block = 64 q rows (4 waves x 16). Window union [qb-128, qb+192) = 320 rows.
// K: 320 rows x 128B, granule-XOR swizzled. V (transposed): 64 rows x 320 cols
// = 640B/row, granule-XOR swizzled. K+V = exactly 80 KiB -> 2 blocks/CU.
// P overlays the K buffer after the QK barrier.
__global__ __launch_bounds__(256) void attn_mfma(
    const u16* __restrict__ qkv,
    u16* __restrict__ aout)   // (B, S, D) bf16
{
    __shared__ char lds[81920];
    char* kbuf = lds;             // 40960: K window, 8 granules/row
    char* vbuf = lds + 40960;     // 40960: Vt window, 40 granules/row

    const int tid  = threadIdx.x;
    const int lane = tid & 63;
    const int wave = tid >> 6;
    const int col  = lane & 15;
    const int hi   = lane >> 4;

    // XCD-aware bijective swizzle: 1024 blocks, 8 XCDs, 128 per XCD
    const int p = blockIdx.x;
    const int l = (p & 7) * 128 + (p >> 3);
    const int qblk = l & 63;
    const int bh   = l >> 6;

    const int qbase  = qblk * 64 + wave * 16;
    const int wbaseB = qblk * 64 - 128;   // block window base
    const int wbase  = qbase - 128;       // wave window base

    const size_t plane = (size_t)BB * HH * SS * HDIM;
    const u16* qp = qkv;
    const u16* kp = qp + plane;
    const u16* vt = qp + 2 * plane;       // Vt[bh][hd][s]
    const size_t base = (size_t)bh * SS * HDIM;

    // Q fragments (issue early)
    const u16* qrow = qp + base + (size_t)(qbase + col) * HDIM;
    Frag qaL, qaH;
    qaL.u = *(const uint4*)(qrow + hi * 8);
    qaH.u = *(const uint4*)(qrow + 32 + hi * 8);

    // ---- K staging: 2560 granules (320 rows x 8), src pre-swizzled g^(r&7)
    #pragma unroll
    for (int rnd = 0; rnd < 10; ++rnd) {
        int f = rnd * 256 + tid;
        int r = f >> 3, g = f & 7;
        int srow = min(max(wbaseB + r, 0), SS - 1);
        int sg = g ^ (r & 7);
        gload16(kp + base + (size_t)srow * HDIM + sg * 8,
                kbuf + (rnd * 256 + wave * 64) * 16);
    }
    // ---- V staging: 2560 granules (64 rows x 40), src pre-swizzled g^(r&7)
    #pragma unroll
    for (int rnd = 0; rnd < 10; ++rnd) {
        int f = rnd * 256 + tid;
        int r = f / 40, g = f - r * 40;
        int s = wbaseB + (g ^ (r & 7)) * 8;
        s = min(max(s, 0), SS - 8);                 // clamped region has P=0
        gload16(vt + ((size_t)bh * HDIM + r) * SS + s,
                vbuf + (rnd * 256 + wave * 64) * 16);
    }
    __syncthreads();

    // ---- scores from LDS (granule-XOR read; wr&7 == col&7)
    const int c7 = col & 7;
    f32x4 sc[17];
    #pragma unroll
    for (int t = 0; t < 17; ++t) {
        int wr = wave * 16 + 16 * t + col;        // 0..319
        const char* kb = kbuf + wr * 128;
        Frag kbL, kbH;
        kbL.u = *(const uint4*)(kb + ((hi ^ c7) * 16));
        kbH.u = *(const uint4*)(kb + (((hi | 4) ^ c7) * 16));
        f32x4 z = {0.f, 0.f, 0.f, 0.f};
        __builtin_amdgcn_s_setprio(1);
        f32x4 a = __builtin_amdgcn_mfma_f32_16x16x32_bf16(qaL.v, kbL.v, z, 0, 0, 0);
        sc[t] = __builtin_amdgcn_mfma_f32_16x16x32_bf16(qaH.v, kbH.v, a, 0, 0, 0);
        __builtin_amdgcn_s_setprio(0);
    }

    // ---- mask + scale
    #pragma unroll
    for (int t = 0; t < 17; ++t) {
        int j = wbase + 16 * t + col;
        #pragma unroll
        for (int r = 0; r < 4; ++r) {
            int i = qbase + hi * 4 + r;
            bool ok = (j >= 0) && (j < SS) && (j >= i - WINW) && (j < i + WINW);
            sc[t][r] = ok ? sc[t][r] * 0.125f : -1e30f;
        }
    }

    // ---- softmax (reduce across lane bits 0..3)
    float mrow[4], srow4[4];
    #pragma unroll
    for (int r = 0; r < 4; ++r) {
        float m = sc[0][r];
        #pragma unroll
        for (int t = 1; t < 17; ++t) m = fmaxf(m, sc[t][r]);
        m = fmaxf(m, __shfl_xor(m, 1));
        m = fmaxf(m, __shfl_xor(m, 2));
        m = fmaxf(m, __shfl_xor(m, 4));
        m = fmaxf(m, __shfl_xor(m, 8));
        mrow[r] = m;
    }
    #pragma unroll
    for (int r = 0; r < 4; ++r) {
        float s = 0.f;
        #pragma unroll
        for (int t = 0; t < 17; ++t) {
            float e = __expf(sc[t][r] - mrow[r]);
            sc[t][r] = e;
            s += e;
        }
        s += __shfl_xor(s, 1);
        s += __shfl_xor(s, 2);
        s += __shfl_xor(s, 4);
        s += __shfl_xor(s, 8);
        srow4[r] = 1.f / s;
    }

    // ---- all waves done reading K; P overlays kbuf
    __syncthreads();
    u16* plds = (u16*)kbuf + (size_t)wave * 16 * 296;   // [16][296] per wave

    #pragma unroll
    for (int t = 0; t < 17; ++t)
        #pragma unroll
        for (int r = 0; r < 4; ++r)
            plds[(hi * 4 + r) * 296 + 16 * t + col] = (u16)f2bf(sc[t][r] * srow4[r]);
    #pragma unroll
    for (int u = 0; u < 4; ++u)
        plds[col * 296 + 272 + hi * 4 + u] = 0;

    // ---- PV from LDS: out(16q x 64d) = P(16x288) @ V(288x64)
    f32x4 o[4];
    #pragma unroll
    for (int n = 0; n < 4; ++n) o[n] = (f32x4){0.f, 0.f, 0.f, 0.f};

    const u16* prow = plds + col * 296;
    #pragma unroll
    for (int ks = 0; ks < 9; ++ks) {
        Frag pa;
        pa.u = *(const uint4*)(prow + 32 * ks + hi * 8);
        int gbl = min(2 * wave + 4 * ks + hi, 39);   // clamp: clamped pos has P=0
        #pragma unroll
        for (int n = 0; n < 4; ++n) {
            int row = 16 * n + col;
            Frag vb;
            vb.u = *(const uint4*)(vbuf + row * 640 + ((gbl ^ (row & 7)) * 16));
            __builtin_amdgcn_s_setprio(1);
            o[n] = __builtin_amdgcn_mfma_f32_16x16x32_bf16(pa.v, vb.v, o[n], 0, 0, 0);
            __builtin_amdgcn_s_setprio(0);
        }
    }

    const int b = bh >> 3, h = bh & 7;
    #pragma unroll
    for (int n = 0; n < 4; ++n)
        #pragma unroll
        for (int r = 0; r < 4; ++r) {
            int i = qbase + hi * 4 + r;
            aout[((size_t)b * SS + i) * DD + h * HDIM + 16 * n + col] = (u16)f2bf(o[n][r]);
        }
}

extern "C" void kernel_launch(void* const* d_in, const int* in_sizes, int n_in,
                              void* d_out, int out_size, void* d_ws, size_t ws_size,
                              hipStream_t stream) {
    const float* x  = (const float*)d_in[0];
    const float* Wq = (const float*)d_in[1];
    const float* bq = (const float*)d_in[2];
    const float* Wk = (const float*)d_in[3];
    const float* bk = (const float*)d_in[4];
    const float* Wv = (const float*)d_in[5];
    const float* bv = (const float*)d_in[6];
    const float* Wo = (const float*)d_in[7];
    const float* bo = (const float*)d_in[8];
    float* out = (float*)d_out;

    char* ws = (char*)d_ws;
    const size_t plane = (size_t)BB * HH * SS * HDIM;
    u16* qkv = (u16*)ws;
    u16* Xb  = (u16*)(ws + 3 * plane * sizeof(u16));
    u16* aout = Xb;                                     // alias: Xb dead after gemm_qkv
    u16* Wt  = (u16*)(ws + 3 * plane * sizeof(u16) + (size_t)BB * SS * DD * sizeof(u16));
    u16* Wot = Wt + (size_t)3 * 512 * 512;

    dim3 blk(256);
    convert_x<<<dim3(2048), blk, 0, stream>>>(x, Xb);
    transpose_w<<<dim3(8, 8, 4), blk, 0, stream>>>(Wq, Wk, Wv, Wo, Wt, Wot);
    gemm_bf16<0><<<dim3(64, 12), blk, 0, stream>>>(Xb, Wt, bq, bk, bv, qkv);
    attn_mfma<<<dim3(1024), blk, 0, stream>>>(qkv, aout);
    gemm_bf16<1><<<dim3(64, 4), blk, 0, stream>>>(aout, Wot, bo, bo, bo, out);
}